// Round 1
// 35.407 us; speedup vs baseline: 1.0052x; 1.0052x over previous
//
#include <hip/hip_runtime.h>

#define DIM 64
#define HW 4096          // 64*64
#define NELEM 8388608.0f // 32*64*4096
#define NBLK 2048

typedef __attribute__((ext_vector_type(8))) short short8;   // 8 x bf16
typedef __attribute__((ext_vector_type(4))) float f32x4;

__device__ __forceinline__ unsigned short f2bf(float f) {
  unsigned int u = __builtin_bit_cast(unsigned int, f);
  u += 0x7fffu + ((u >> 16) & 1u);            // round-to-nearest-even
  return (unsigned short)(u >> 16);
}

__device__ __forceinline__ float wave_sum(float v) {
  #pragma unroll
  for (int off = 32; off >= 1; off >>= 1) v += __shfl_xor(v, off);
  return v;
}

// ws layout (bytes):
//  [0,      65536)  A-frags: bf16(-2*codebook), MFMA-fragment order (L2-hot)
//  [65536,  67584)  cnorm fp32 [512]
//  [67584,  75776)  per-block partial sum(x^2)      (2048 floats)
//  [75776,  83968)  per-block partial sum(min d2')  (2048 floats)

// ---------------- prep: codebook -> fragment order (once per call) ---------
__global__ void vq_prep(const float* __restrict__ CB,
                        unsigned short* __restrict__ aFg,
                        float* __restrict__ cn) {
  const int t = threadIdx.x;
  const int s = blockIdx.x * 512 + t;     // 0..4095 fragment slots
  const int chunk = s >> 7, ks = (s >> 6) & 1, ls = s & 63;
  const int code = chunk * 16 + (ls & 15);
  const int d0 = ks * 32 + (ls >> 4) * 8;
  const float* cp = CB + code * DIM + d0;
  float4 u0 = *(const float4*)cp;
  float4 u1 = *(const float4*)(cp + 4);
  short8 p;
  p[0]=(short)f2bf(-2.f*u0.x); p[1]=(short)f2bf(-2.f*u0.y);
  p[2]=(short)f2bf(-2.f*u0.z); p[3]=(short)f2bf(-2.f*u0.w);
  p[4]=(short)f2bf(-2.f*u1.x); p[5]=(short)f2bf(-2.f*u1.y);
  p[6]=(short)f2bf(-2.f*u1.z); p[7]=(short)f2bf(-2.f*u1.w);
  *(short8*)&aFg[s * 8] = p;
  if (blockIdx.x == 0) {                  // exact fp32 ||c_k||^2
    const float* c2 = CB + t * DIM;
    float sn = 0.f;
    #pragma unroll
    for (int i = 0; i < 16; ++i) {
      float4 u = *(const float4*)(c2 + i * 4);
      sn += u.x*u.x + u.y*u.y + u.z*u.z + u.w*u.w;
    }
    cn[t] = sn;
  }
}

// ---- main: 2048 blocks x 4 waves; 64-col tile; codes split across waves ----
// launch_bounds(256,4): 128-VGPR budget (no spill; (256,8)/(256,6) spilled).
// NO atomics/fences here: 2048 same-address device atomics + threadfence
// serialized at ~100us across r3-r6 (cross-XCD coherence convoy).
//
// NEW (this round): X is staged into LDS directly in B-FRAGMENT order with an
// XOR slot swizzle, so the per-wave fragment load is 8x ds_read_b128 instead
// of 64x ds_read_u16 + ~32 pack ops.  Slot s (16B) = (cb*2+ks)*64 + g*16 +
// lcol, holding X[ks*32+g*8+j][cb*16+lcol] (j=0..7 bf16).  Physical slot =
// s ^ ((s>>3)&7): both the b128 writes (8 distinct bank-groups/phase) and the
// b128 reads (bijection onto 64 consecutive slots) are conflict-free.
__global__ __launch_bounds__(256, 4)
void vq_main(const float* __restrict__ X, const float* __restrict__ CB,
             const unsigned short* __restrict__ aFg,
             const float* __restrict__ cng,
             float* __restrict__ out,
             float* __restrict__ pA, float* __restrict__ pB) {
  __shared__ __align__(16) unsigned short XF[8 * 64 * 8]; // 8,192 B frag-order
  __shared__ float mW[4][64];                 // per-wave packed mins per col
  __shared__ float red[8];

  const int t   = threadIdx.x;
  const int bid = blockIdx.x;
  // XCD-chunked swizzle: XCD x owns logical blocks [x*256,(x+1)*256)
  const int L   = ((bid & 7) << 8) | (bid >> 3);
  const int n   = L >> 6;                     // image
  const int hw0 = (L & 63) << 6;              // 64-col tile
  const int wv  = t >> 6, lane = t & 63;
  const int g   = lane >> 4, lcol = lane & 15;

  const float* Xg = X + n * (DIM * HW) + hw0;

  // ---- stage X tile fp32->bf16 straight into fragment order --------------
  // thread t: d-rows db8*8..db8*8+7, cols 2*cp, 2*cp+1
  const int db8 = t >> 5;                     // 0..7
  const int cp  = t & 31;                     // 0..31
  const int kss = db8 >> 2, gs = db8 & 3;
  float2 v[8];
  #pragma unroll
  for (int j = 0; j < 8; ++j)
    v[j] = *(const float2*)(Xg + (db8 * 8 + j) * HW + cp * 2);
  float sx2 = 0.f;
  #pragma unroll
  for (int j = 0; j < 8; ++j)
    sx2 += v[j].x * v[j].x + v[j].y * v[j].y;
  #pragma unroll
  for (int ci = 0; ci < 2; ++ci) {
    const int c = cp * 2 + ci;
    const int slot = ((c >> 4) * 2 + kss) * 64 + gs * 16 + (c & 15);
    const int swz  = slot ^ ((slot >> 3) & 7);
    short8 w;
    #pragma unroll
    for (int j = 0; j < 8; ++j)
      w[j] = (short)f2bf(ci ? v[j].y : v[j].x);
    *(short8*)&XF[swz * 8] = w;
  }
  __syncthreads();

  // ---- B-frags from LDS: 8x ds_read_b128, conflict-free ------------------
  const int s64  = g * 16 + lcol;             // slot within sub-block = lane
  const int swzl = s64 ^ ((s64 >> 3) & 7);
  short8 bfrag[4][2];
  #pragma unroll
  for (int cb = 0; cb < 4; ++cb) {
    #pragma unroll
    for (int ks = 0; ks < 2; ++ks)
      bfrag[cb][ks] = *(const short8*)&XF[((cb * 2 + ks) * 64 + swzl) * 8];
  }

  // ---- this wave scans 128 codes = 8 chunks of 16, over all 64 cols ----
  float m1[4];
  #pragma unroll
  for (int cb = 0; cb < 4; ++cb) m1[cb] = 3.0e38f;

  const int chunk0 = wv * 8;
  #pragma unroll 4
  for (int i = 0; i < 8; ++i) {
    const int chunk = chunk0 + i;
    const short8 a0 = *(const short8*)&aFg[((chunk*2 + 0) * 64 + lane) * 8];
    const short8 a1 = *(const short8*)&aFg[((chunk*2 + 1) * 64 + lane) * 8];
    const int codebase = chunk * 16 + g * 4;
    const f32x4 cn = *(const f32x4*)&cng[codebase];
    #pragma unroll
    for (int cb = 0; cb < 4; ++cb) {
      f32x4 acc = cn;
      acc = __builtin_amdgcn_mfma_f32_16x16x32_bf16(a0, bfrag[cb][0], acc, 0, 0, 0);
      acc = __builtin_amdgcn_mfma_f32_16x16x32_bf16(a1, bfrag[cb][1], acc, 0, 0, 0);
      #pragma unroll
      for (int r = 0; r < 4; ++r) {
        unsigned int vb = __builtin_bit_cast(unsigned int, acc[r]);
        // complementary-mask form -> single v_bfi_b32
        vb = (vb & 0xFFFFFE00u) | ((unsigned)(codebase + r) & 0x1FFu);
        m1[cb] = fminf(m1[cb], __builtin_bit_cast(float, vb));
      }
    }
  }

  // combine lane-groups (disjoint code subsets, same col)
  #pragma unroll
  for (int cb = 0; cb < 4; ++cb) {
    m1[cb] = fminf(m1[cb], __shfl_xor(m1[cb], 16));
    m1[cb] = fminf(m1[cb], __shfl_xor(m1[cb], 32));
    if (g == 0) mW[wv][cb * 16 + lcol] = m1[cb];
  }
  __syncthreads();

  // ---- final per-col argmin over the 4 wave code-subsets ----
  const float p = fminf(fminf(mW[0][lane], mW[1][lane]),
                        fminf(mW[2][lane], mW[3][lane]));
  const unsigned int b = __builtin_bit_cast(unsigned int, p);
  const int k = (int)(b & 511u);
  const float minval = __builtin_bit_cast(float, b & 0xFFFFFE00u);

  // ---- epilogue: col = lane, wave wv writes d-rows [wv*16, wv*16+16) ----
  const float* cq = CB + k * DIM + wv * 16;   // L2-hot gather
  float* op = out + 1 + n * (DIM * HW) + hw0 + lane;
  #pragma unroll
  for (int i = 0; i < 4; ++i) {
    float4 u = *(const float4*)(cq + i * 4);
    op[(wv*16 + i*4 + 0) * HW] = u.x;         // 256B coalesced per store
    op[(wv*16 + i*4 + 1) * HW] = u.y;
    op[(wv*16 + i*4 + 2) * HW] = u.z;
    op[(wv*16 + i*4 + 3) * HW] = u.w;
  }

  // ---- loss partials (no atomics; vq_fin reduces) ----
  float w1 = wave_sum(sx2);
  if (lane == 0) red[wv] = w1;
  if (wv == 0) {
    float w2 = wave_sum(minval);              // each col counted once
    if (lane == 0) red[4] = w2;
  }
  __syncthreads();
  if (t == 0) {
    pA[bid] = red[0] + red[1] + red[2] + red[3];
    pB[bid] = red[4];
  }
}

__global__ void vq_fin(const float* __restrict__ pA,
                       const float* __restrict__ pB,
                       float* __restrict__ out) {
  const int t = threadIdx.x;                  // 512 threads
  float4 a = *(const float4*)&pA[t * 4];
  float4 c = *(const float4*)&pB[t * 4];
  float v = a.x + a.y + a.z + a.w + c.x + c.y + c.z + c.w;
  v = wave_sum(v);
  __shared__ float r[8];
  if ((t & 63) == 0) r[t >> 6] = v;
  __syncthreads();
  if (t == 0) {
    float s = 0.f;
    #pragma unroll
    for (int i = 0; i < 8; ++i) s += r[i];
    out[0] = 1.25f * s * (1.0f / NELEM);
  }
}

extern "C" void kernel_launch(void* const* d_in, const int* in_sizes, int n_in,
                              void* d_out, int out_size, void* d_ws, size_t ws_size,
                              hipStream_t stream) {
  const float* X  = (const float*)d_in[0];   // [32,64,64,64] fp32
  const float* CB = (const float*)d_in[1];   // [512,64] fp32
  float* out = (float*)d_out;                // [0]=loss, [1..]=quantized_st
  char* ws = (char*)d_ws;
  unsigned short* aFg = (unsigned short*)ws;
  float* cn = (float*)(ws + 65536);
  float* pA = (float*)(ws + 67584);
  float* pB = (float*)(ws + 75776);
  (void)in_sizes; (void)n_in; (void)out_size; (void)ws_size;

  vq_prep<<<8, 512, 0, stream>>>(CB, aFg, cn);
  vq_main<<<NBLK, 256, 0, stream>>>(X, CB, aFg, cn, out, pA, pB);
  vq_fin<<<1, 512, 0, stream>>>(pA, pB, out);
}

// Round 2
// 34.254 us; speedup vs baseline: 1.0390x; 1.0337x over previous
//
#include <hip/hip_runtime.h>

#define DIM 64
#define HW 4096          // 64*64
#define NELEM 8388608.0f // 32*64*4096
#define NBLK 1024        // 128-col tiles now

typedef __attribute__((ext_vector_type(8))) short short8;   // 8 x bf16
typedef __attribute__((ext_vector_type(4))) float f32x4;
typedef __attribute__((ext_vector_type(2))) float f32x2;

__device__ __forceinline__ unsigned short f2bf(float f) {
  unsigned int u = __builtin_bit_cast(unsigned int, f);
  u += 0x7fffu + ((u >> 16) & 1u);            // round-to-nearest-even
  return (unsigned short)(u >> 16);
}

__device__ __forceinline__ float wave_sum(float v) {
  #pragma unroll
  for (int off = 32; off >= 1; off >>= 1) v += __shfl_xor(v, off);
  return v;
}

// ws layout (bytes):
//  [0,      65536)  A-frags: bf16(-2*codebook), MFMA-fragment order (L2-hot)
//  [65536,  67584)  cnorm fp32 [512]
//  [67584,  71680)  per-block partial sum(x^2)      (1024 floats)
//  [75776,  79872)  per-block partial sum(min d2')  (1024 floats)

// ---------------- prep: codebook -> fragment order (once per call) ---------
__global__ void vq_prep(const float* __restrict__ CB,
                        unsigned short* __restrict__ aFg,
                        float* __restrict__ cn) {
  const int t = threadIdx.x;
  const int s = blockIdx.x * 512 + t;     // 0..4095 fragment slots
  const int chunk = s >> 7, ks = (s >> 6) & 1, ls = s & 63;
  const int code = chunk * 16 + (ls & 15);
  const int d0 = ks * 32 + (ls >> 4) * 8;
  const float* cp = CB + code * DIM + d0;
  float4 u0 = *(const float4*)cp;
  float4 u1 = *(const float4*)(cp + 4);
  short8 p;
  p[0]=(short)f2bf(-2.f*u0.x); p[1]=(short)f2bf(-2.f*u0.y);
  p[2]=(short)f2bf(-2.f*u0.z); p[3]=(short)f2bf(-2.f*u0.w);
  p[4]=(short)f2bf(-2.f*u1.x); p[5]=(short)f2bf(-2.f*u1.y);
  p[6]=(short)f2bf(-2.f*u1.z); p[7]=(short)f2bf(-2.f*u1.w);
  *(short8*)&aFg[s * 8] = p;
  if (blockIdx.x == 0) {                  // exact fp32 ||c_k||^2
    const float* c2 = CB + t * DIM;
    float sn = 0.f;
    #pragma unroll
    for (int i = 0; i < 16; ++i) {
      float4 u = *(const float4*)(c2 + i * 4);
      sn += u.x*u.x + u.y*u.y + u.z*u.z + u.w*u.w;
    }
    cn[t] = sn;
  }
}

// ---- main: 1024 blocks x 4 waves; 128-col tile; codes split across waves --
// R1 theory: aFg (64KB) was re-read per block from off-L2 (X/out streams
// evict it).  (1) 128-col tile + resident bfrag[2][4][2] halves aFg traffic
// (134->67 MB) and halves per-block fixed costs; (2) nontemporal X loads +
// out stores keep aFg/CB/cng L2-resident; (3) 1024 blocks = exactly 4/CU,
// one fully-resident round.
// NO atomics/fences (2048 same-addr device atomics ~100us convoy, r3-r6).
__global__ __launch_bounds__(256, 4)
void vq_main(const float* __restrict__ X, const float* __restrict__ CB,
             const unsigned short* __restrict__ aFg,
             const float* __restrict__ cng,
             float* __restrict__ out,
             float* __restrict__ pA, float* __restrict__ pB) {
  __shared__ __align__(16) unsigned short XF[16 * 64 * 8]; // 16 KB frag-order
  __shared__ float mW[4][128];                // per-wave packed mins per col
  __shared__ float red[8];

  const int t   = threadIdx.x;
  const int bid = blockIdx.x;
  // XCD-chunked swizzle: XCD x owns logical blocks [x*128,(x+1)*128)
  const int L   = ((bid & 7) << 7) | (bid >> 3);
  const int n   = L >> 5;                     // image (32 tiles of 128 cols)
  const int hw0 = (L & 31) << 7;              // 128-col tile
  const int wv  = t >> 6, lane = t & 63;
  const int g   = lane >> 4, lcol = lane & 15;

  const float* Xg = X + n * (DIM * HW) + hw0;

  // ---- stage X tile fp32->bf16 straight into fragment order --------------
  // thread t: d-rows db8*8..db8*8+7, cols {h*64 + cp*2, +1} for h=0,1
  const int db8 = t >> 5;                     // 0..7
  const int cp  = t & 31;                     // 0..31
  const int kss = db8 >> 2, gs = db8 & 3;
  f32x2 v[2][8];
  #pragma unroll
  for (int h = 0; h < 2; ++h)
    #pragma unroll
    for (int j = 0; j < 8; ++j)
      v[h][j] = __builtin_nontemporal_load(
          (const f32x2*)(Xg + (db8 * 8 + j) * HW + h * 64 + cp * 2));
  float sx2 = 0.f;
  #pragma unroll
  for (int h = 0; h < 2; ++h)
    #pragma unroll
    for (int j = 0; j < 8; ++j)
      sx2 += v[h][j].x * v[h][j].x + v[h][j].y * v[h][j].y;
  #pragma unroll
  for (int h = 0; h < 2; ++h) {
    #pragma unroll
    for (int ci = 0; ci < 2; ++ci) {
      const int cl   = cp * 2 + ci;           // 0..63 within half
      const int cb   = h * 4 + (cl >> 4);     // 0..7 col-block
      const int slot = (cb * 2 + kss) * 64 + gs * 16 + (cl & 15);
      const int swz  = slot ^ ((slot >> 3) & 7);
      short8 w;
      #pragma unroll
      for (int j = 0; j < 8; ++j)
        w[j] = (short)f2bf(ci ? v[h][j].y : v[h][j].x);
      *(short8*)&XF[swz * 8] = w;
    }
  }
  __syncthreads();

  // ---- B-frags from LDS: 16x ds_read_b128, conflict-free, resident -------
  const int swzl = lane ^ ((lane >> 3) & 7);
  short8 bfrag[2][4][2];
  #pragma unroll
  for (int h = 0; h < 2; ++h)
    #pragma unroll
    for (int cb2 = 0; cb2 < 4; ++cb2)
      #pragma unroll
      for (int ks = 0; ks < 2; ++ks)
        bfrag[h][cb2][ks] =
            *(const short8*)&XF[(((h * 4 + cb2) * 2 + ks) * 64 + swzl) * 8];

  // ---- this wave scans 128 codes = 8 chunks of 16, over all 128 cols -----
  float m1[8];
  #pragma unroll
  for (int cb = 0; cb < 8; ++cb) m1[cb] = 3.0e38f;

  const int chunk0 = wv * 8;
  #pragma unroll 2
  for (int i = 0; i < 8; ++i) {
    const int chunk = chunk0 + i;
    const short8 a0 = *(const short8*)&aFg[((chunk*2 + 0) * 64 + lane) * 8];
    const short8 a1 = *(const short8*)&aFg[((chunk*2 + 1) * 64 + lane) * 8];
    const int codebase = chunk * 16 + g * 4;
    const f32x4 cn = *(const f32x4*)&cng[codebase];
    #pragma unroll
    for (int h = 0; h < 2; ++h) {
      #pragma unroll
      for (int cb2 = 0; cb2 < 4; ++cb2) {
        f32x4 acc = cn;
        acc = __builtin_amdgcn_mfma_f32_16x16x32_bf16(a0, bfrag[h][cb2][0], acc, 0, 0, 0);
        acc = __builtin_amdgcn_mfma_f32_16x16x32_bf16(a1, bfrag[h][cb2][1], acc, 0, 0, 0);
        #pragma unroll
        for (int r = 0; r < 4; ++r) {
          unsigned int vb = __builtin_bit_cast(unsigned int, acc[r]);
          // complementary-mask form -> single v_bfi_b32
          vb = (vb & 0xFFFFFE00u) | ((unsigned)(codebase + r) & 0x1FFu);
          m1[h * 4 + cb2] = fminf(m1[h * 4 + cb2], __builtin_bit_cast(float, vb));
        }
      }
    }
  }

  // combine lane-groups (disjoint code subsets, same col)
  #pragma unroll
  for (int cb = 0; cb < 8; ++cb) {
    m1[cb] = fminf(m1[cb], __shfl_xor(m1[cb], 16));
    m1[cb] = fminf(m1[cb], __shfl_xor(m1[cb], 32));
    if (g == 0) mW[wv][cb * 16 + lcol] = m1[cb];
  }
  __syncthreads();

  // ---- final per-col argmin + epilogue, two 64-col passes ----------------
  float msum = 0.f;
  #pragma unroll
  for (int h = 0; h < 2; ++h) {
    const int c = h * 64 + lane;
    const float p = fminf(fminf(mW[0][c], mW[1][c]),
                          fminf(mW[2][c], mW[3][c]));
    const unsigned int b = __builtin_bit_cast(unsigned int, p);
    const int k = (int)(b & 511u);
    msum += __builtin_bit_cast(float, b & 0xFFFFFE00u);

    const float* cq = CB + k * DIM + wv * 16; // L2-hot gather
    float* op = out + 1 + n * (DIM * HW) + hw0 + c;
    #pragma unroll
    for (int i = 0; i < 4; ++i) {
      float4 u = *(const float4*)(cq + i * 4);
      __builtin_nontemporal_store(u.x, &op[(wv*16 + i*4 + 0) * HW]);
      __builtin_nontemporal_store(u.y, &op[(wv*16 + i*4 + 1) * HW]);
      __builtin_nontemporal_store(u.z, &op[(wv*16 + i*4 + 2) * HW]);
      __builtin_nontemporal_store(u.w, &op[(wv*16 + i*4 + 3) * HW]);
    }
  }

  // ---- loss partials (no atomics; vq_fin reduces) ----
  float w1 = wave_sum(sx2);
  if (lane == 0) red[wv] = w1;
  if (wv == 0) {
    float w2 = wave_sum(msum);                // each col counted once
    if (lane == 0) red[4] = w2;
  }
  __syncthreads();
  if (t == 0) {
    pA[bid] = red[0] + red[1] + red[2] + red[3];
    pB[bid] = red[4];
  }
}

__global__ void vq_fin(const float* __restrict__ pA,
                       const float* __restrict__ pB,
                       float* __restrict__ out) {
  const int t = threadIdx.x;                  // 512 threads, 1024 partials
  f32x2 a = *(const f32x2*)&pA[t * 2];
  f32x2 c = *(const f32x2*)&pB[t * 2];
  float v = a.x + a.y + c.x + c.y;
  v = wave_sum(v);
  __shared__ float r[8];
  if ((t & 63) == 0) r[t >> 6] = v;
  __syncthreads();
  if (t == 0) {
    float s = 0.f;
    #pragma unroll
    for (int i = 0; i < 8; ++i) s += r[i];
    out[0] = 1.25f * s * (1.0f / NELEM);
  }
}

extern "C" void kernel_launch(void* const* d_in, const int* in_sizes, int n_in,
                              void* d_out, int out_size, void* d_ws, size_t ws_size,
                              hipStream_t stream) {
  const float* X  = (const float*)d_in[0];   // [32,64,64,64] fp32
  const float* CB = (const float*)d_in[1];   // [512,64] fp32
  float* out = (float*)d_out;                // [0]=loss, [1..]=quantized_st
  char* ws = (char*)d_ws;
  unsigned short* aFg = (unsigned short*)ws;
  float* cn = (float*)(ws + 65536);
  float* pA = (float*)(ws + 67584);
  float* pB = (float*)(ws + 75776);
  (void)in_sizes; (void)n_in; (void)out_size; (void)ws_size;

  vq_prep<<<8, 512, 0, stream>>>(CB, aFg, cn);
  vq_main<<<NBLK, 256, 0, stream>>>(X, CB, aFg, cn, out, pA, pB);
  vq_fin<<<1, 512, 0, stream>>>(pA, pB, out);
}